// Round 5
// baseline (280.340 us; speedup 1.0000x reference)
//
#include <hip/hip_runtime.h>
#include <hip/hip_bf16.h>

#define RES 300
#define NPLANE (RES * RES)   // 90000
#define NC_A 48
#define APP_DIM 27
#define KDIM 144             // 3 * NC_A
#define KS 168               // prod LDS row stride in shorts (336 B, 16B-aligned)
#define CWS 20               // cw row stride in floats (even -> 8B-aligned float2)

#define PT_TILES 1407        // ceil(90000 / 64) p-tiles per plane
#define NPB2 (3 * PT_TILES)  // 4221 plane-transpose blocks

#define NBINS 32768          // 5 bits/axis Morton bins

// bf16 (packed in uint halves) -> f32
__device__ __forceinline__ float bf_lo(unsigned int u) { return __uint_as_float(u << 16); }
__device__ __forceinline__ float bf_hi(unsigned int u) { return __uint_as_float(u & 0xffff0000u); }

// 5-bit spread to every 3rd bit: b4..b0 -> positions 12,9,6,3,0
__device__ __forceinline__ unsigned int spread5(unsigned int v) {
  return (v & 1u) | ((v & 2u) << 2) | ((v & 4u) << 4) |
         ((v & 8u) << 6) | ((v & 16u) << 8);
}
__device__ __forceinline__ unsigned int bin_key(float x, float y, float z) {
  int qx = min(31, max(0, (int)((x + 1.f) * 16.f)));
  int qy = min(31, max(0, (int)((y + 1.f) * 16.f)));
  int qz = min(31, max(0, (int)((z + 1.f) * 16.f)));
  return (spread5((unsigned)qz) << 2) | (spread5((unsigned)qy) << 1) |
         spread5((unsigned)qx);
}

// ---------------------------------------------------------------------------
// Unified prep kernel (unchanged — passing since R1).
// ---------------------------------------------------------------------------
__global__ __launch_bounds__(256) void prep(
    const float* __restrict__ plane, const float* __restrict__ line,
    const float* __restrict__ W,
    unsigned int* __restrict__ TpUo, unsigned int* __restrict__ TlP,
    __hip_bfloat16* __restrict__ Wg) {
  __shared__ __align__(16) unsigned int lt[64 * 65];
  const int blk = blockIdx.x;
  const int tid = threadIdx.x;

  if (blk < NPB2) {
    const int i  = blk / PT_TILES;
    const int t0 = blk - i * PT_TILES;
    const int p0 = t0 * 64;

    const int cb   = (tid >> 4) * 4;
    const int poff = (tid & 15) * 4;
    const bool ok  = (p0 + poff) < NPLANE;

    const float* src = plane + (size_t)(i * 64 + cb) * NPLANE + p0 + poff;
    float4 v0, v1, v2, v3;
    v0 = v1 = v2 = v3 = make_float4(0.f, 0.f, 0.f, 0.f);
    if (ok) {
      v0 = *(const float4*)(src);
      v1 = *(const float4*)(src + NPLANE);
      v2 = *(const float4*)(src + 2 * NPLANE);
      v3 = *(const float4*)(src + 3 * NPLANE);
    }
    const int col = (tid >> 4) * 2;
    const float* f0 = &v0.x; const float* f1 = &v1.x;
    const float* f2 = &v2.x; const float* f3 = &v3.x;
    #pragma unroll
    for (int j = 0; j < 4; ++j) {
      __hip_bfloat162 ha, hb;
      ha.x = __float2bfloat16(f0[j]);
      ha.y = __float2bfloat16(f1[j]);
      hb.x = __float2bfloat16(f2[j]);
      hb.y = __float2bfloat16(f3[j]);
      uint2 u;
      u.x = *(unsigned int*)&ha;
      u.y = *(unsigned int*)&hb;
      *(uint2*)&lt[(poff + j) * 34 + col] = u;
    }
    __syncthreads();
    #pragma unroll
    for (int pass = 0; pass < 2; ++pass) {
      int p  = (tid >> 3) + pass * 32;
      int c4 = (tid & 7) * 4;
      if (p0 + p < NPLANE) {
        uint2 a = *(const uint2*)&lt[p * 34 + c4];
        uint2 b = *(const uint2*)&lt[p * 34 + c4 + 2];
        uint4 w; w.x = a.x; w.y = a.y; w.z = b.x; w.w = b.y;
        *(uint4*)&TpUo[((size_t)(i * NPLANE + p0 + p)) * 32 + c4] = w;
      }
    }
  } else if (blk < NPB2 + 15) {
    const int b  = blk - NPB2;
    const int i  = b / 5;
    const int y0 = (b % 5) * 64;
    const int yl = tid & 63;
    const int cq = tid >> 6;
    #pragma unroll
    for (int k = 0; k < 16; ++k) {
      int c = cq * 16 + k;
      int y = y0 + yl;
      float a = 0.f, bv = 0.f;
      if (y < RES) {
        const float* row = line + (i * 64 + c) * RES;
        a  = row[y];
        bv = row[min(y + 1, RES - 1)];
      }
      __hip_bfloat162 h;
      h.x = __float2bfloat16(a);
      h.y = __float2bfloat16(bv);
      lt[yl * 65 + c] = *(unsigned int*)&h;
    }
    __syncthreads();
    #pragma unroll
    for (int k = 0; k < 16; ++k) {
      int ylc = k * 4 + cq;
      int c   = tid & 63;
      int y   = y0 + ylc;
      if (y < RES) TlP[((size_t)i * RES + y) * 64 + c] = lt[ylc * 65 + c];
    }
  } else {
    for (int idx = tid; idx < 2 * 5 * 64 * 8; idx += 256) {
      int j    = idx & 7;
      int lane = (idx >> 3) & 63;
      int kt   = (idx >> 9) % 5;
      int tile = idx / (5 * 64 * 8);
      int n = tile * 16 + (lane & 15);
      int k = kt * 32 + (lane >> 4) * 8 + j;
      float v = (n < APP_DIM && k < KDIM) ? W[n * KDIM + k] : 0.f;
      Wg[idx] = __float2bfloat16(v);
    }
  }
}

// ---------------------------------------------------------------------------
// Morton-bin counting sort: zero-hist -> histogram -> 1-block scan ->
// scatter (pre-gathers {xyz, n} into sorted float4 so the main kernel's
// phase-0 reads stay coalesced). Any permutation is correct by construction.
// ---------------------------------------------------------------------------
__global__ __launch_bounds__(256) void zero_hist(unsigned int* __restrict__ hist) {
  hist[blockIdx.x * 256 + threadIdx.x] = 0u;
}

__global__ __launch_bounds__(256) void bin_hist(
    const float* __restrict__ xyz, unsigned int* __restrict__ hist, int n_total) {
  int n = blockIdx.x * 256 + threadIdx.x;
  if (n < n_total) {
    unsigned int k = bin_key(xyz[3 * n], xyz[3 * n + 1], xyz[3 * n + 2]);
    atomicAdd(&hist[k], 1u);
  }
}

__global__ __launch_bounds__(256) void bin_scan(unsigned int* __restrict__ hist) {
  __shared__ unsigned int sums[256];
  const int t = threadIdx.x;
  // serial sum over this thread's 128 bins
  unsigned int s = 0;
  for (int k = 0; k < 128; ++k) s += hist[t * 128 + k];
  sums[t] = s;
  __syncthreads();
  // Hillis-Steele inclusive scan over 256 partials
  for (int off = 1; off < 256; off <<= 1) {
    unsigned int v = (t >= off) ? sums[t - off] : 0u;
    __syncthreads();
    if (t >= off) sums[t] += v;
    __syncthreads();
  }
  unsigned int excl = (t == 0) ? 0u : sums[t - 1];
  // rewrite this thread's bins to exclusive prefix
  for (int k = 0; k < 128; ++k) {
    unsigned int h = hist[t * 128 + k];
    hist[t * 128 + k] = excl;
    excl += h;
  }
}

__global__ __launch_bounds__(256) void bin_scatter(
    const float* __restrict__ xyz, unsigned int* __restrict__ hist,
    float4* __restrict__ xyzS, int n_total) {
  int n = blockIdx.x * 256 + threadIdx.x;
  if (n < n_total) {
    float x = xyz[3 * n], y = xyz[3 * n + 1], z = xyz[3 * n + 2];
    unsigned int k = bin_key(x, y, z);
    unsigned int pos = atomicAdd(&hist[k], 1u);
    float4 v; v.x = x; v.y = y; v.z = z; v.w = __int_as_float(n);
    xyzS[pos] = v;
  }
}

// ---------------------------------------------------------------------------
// Main kernel: fused gather + blend + sigma + MFMA projection.
// Phase-1 structure = R3 (passing, fastest). New vs R3:
//   * consumes Morton-sorted samples from xyzS (float4 {x,y,z,orig_n});
//   * bijective XCD-chunked block swizzle so each XCD sweeps a contiguous
//     Morton range -> active plane working set fits its 4MB L2;
//   * all outputs written via orig_n (scattered; same-value dup writes on
//     tail slots are benign).
// LDS = 21504 (prod) + 5120 (cw) = 26624 B.
// ---------------------------------------------------------------------------
typedef __attribute__((ext_vector_type(8))) short short8;
typedef __attribute__((ext_vector_type(4))) float f32x4;

__global__ __launch_bounds__(256, 5) void tensorf_main(
    const float4* __restrict__ xyzS, const unsigned int* __restrict__ TpU,
    const unsigned int* __restrict__ TlP, const __hip_bfloat16* __restrict__ Wg,
    float* __restrict__ out, int n_total) {
  __shared__ __hip_bfloat16 prod[64 * KS];
  __shared__ float cw[64 * CWS];

  const int tid  = threadIdx.x;
  const int lane = tid & 63;
  const int wave = tid >> 6;

  // bijective XCD-chunked swizzle (m204 form; nwg = 7813, not /8)
  const int nwg = gridDim.x;
  const int qc  = nwg >> 3, rc = nwg & 7;
  const int xcd = blockIdx.x & 7, kb = blockIdx.x >> 3;
  const int chunk = (xcd < rc ? xcd * (qc + 1) : rc * (qc + 1) + (xcd - rc) * qc) + kb;
  const int n0 = chunk * 64;

  // zero prod k-pad [144,168)
  for (int j = tid; j < 64 * 12; j += 256) {
    int s = j / 12, kk = (j % 12) * 2;
    *(unsigned int*)&prod[s * KS + KDIM + kk] = 0u;
  }

  // Phase 0: per-sample precompute from sorted {xyz, orig_n}.
  if (tid < 64) {
    float4 xs = xyzS[min(n0 + tid, n_total - 1)];
    float crd[3] = {xs.x, xs.y, xs.z};
    const int m0s[3] = {0, 0, 1}, m1s[3] = {1, 2, 2}, vms[3] = {2, 1, 0};
    float* c = &cw[tid * CWS];
    #pragma unroll
    for (int i = 0; i < 3; ++i) {
      float ix = fminf(fmaxf((crd[m0s[i]] + 1.f) * 149.5f, 0.f), 299.f);
      float iy = fminf(fmaxf((crd[m1s[i]] + 1.f) * 149.5f, 0.f), 299.f);
      float ly = fminf(fmaxf((crd[vms[i]] + 1.f) * 149.5f, 0.f), 299.f);
      float x0f = fminf(floorf(ix), 298.f);
      float y0f = fminf(floorf(iy), 298.f);
      float l0f = fminf(floorf(ly), 298.f);
      float wx = ix - x0f, wy = iy - y0f, lwy = ly - l0f;
      int cell = i * NPLANE + (int)y0f * RES + (int)x0f;   // < 2^19
      int lidx = i * RES + (int)l0f;                       // < 2^10
      c[i * 6 + 0] = __int_as_float(cell | (lidx << 19));
      c[i * 6 + 1] = (1.f - wx) * (1.f - wy);
      c[i * 6 + 2] = wx * (1.f - wy);
      c[i * 6 + 3] = (1.f - wx) * wy;
      c[i * 6 + 4] = wx * wy;
      c[i * 6 + 5] = lwy;
    }
    c[18] = xs.w;   // original sample index (bit pattern)
  }
  __syncthreads();

  // Phase 1: 4 iterations, 4 samples/wave-iter, 4 channels/lane (R3 form)
  const int cq = lane & 15;     // channel quad -> channels 4cq..4cq+3
  const int sq = lane >> 4;     // sample slot within iteration group
  const int c4 = cq * 4;

  #pragma unroll 2
  for (int it = 0; it < 4; ++it) {
    const int s = wave * 16 + it * 4 + sq;
    const float* cp = &cw[s * CWS];

    // batched load phase: issue all 15 VMEM ops (36 dwords) before any use
    uint2 u00[3], u01[3], u10[3], u11[3];
    uint4 ul[3];
    float wgt[3][5];
    #pragma unroll
    for (int i = 0; i < 3; ++i) {
      float2 q0 = *(const float2*)&cp[i * 6];       // pack, w00
      float2 q1 = *(const float2*)&cp[i * 6 + 2];   // w01, w10
      float2 q2 = *(const float2*)&cp[i * 6 + 4];   // w11, lwy
      int pk   = __float_as_int(q0.x);
      int cell = pk & 0x7FFFF;
      int lidx = pk >> 19;
      int bidx = cell * 32 + cq * 2;                // uint index into TpU
      u00[i] = *(const uint2*)&TpU[bidx];
      u01[i] = *(const uint2*)&TpU[bidx + 32];
      u10[i] = *(const uint2*)&TpU[bidx + RES * 32];
      u11[i] = *(const uint2*)&TpU[bidx + RES * 32 + 32];
      ul[i]  = *(const uint4*)&TlP[(lidx << 6) + c4];
      wgt[i][0] = q0.y; wgt[i][1] = q1.x; wgt[i][2] = q1.y;
      wgt[i][3] = q2.x; wgt[i][4] = q2.y;
    }

    // blend phase
    float dsum = 0.f;
    #pragma unroll
    for (int i = 0; i < 3; ++i) {
      float w00 = wgt[i][0], w01 = wgt[i][1], w10 = wgt[i][2];
      float w11 = wgt[i][3], lw = wgt[i][4];
      // dword 0: channels 4cq, 4cq+1
      {
        float pf_l = w00 * bf_lo(u00[i].x) + w01 * bf_lo(u01[i].x) +
                     w10 * bf_lo(u10[i].x) + w11 * bf_lo(u11[i].x);
        float pf_h = w00 * bf_hi(u00[i].x) + w01 * bf_hi(u01[i].x) +
                     w10 * bf_hi(u10[i].x) + w11 * bf_hi(u11[i].x);
        float lal = bf_lo(ul[i].x), lbl = bf_hi(ul[i].x);
        float lah = bf_lo(ul[i].y), lbh = bf_hi(ul[i].y);
        float lf_l = lal + lw * (lbl - lal);
        float lf_h = lah + lw * (lbh - lah);
        float prl = pf_l * lf_l, prh = pf_h * lf_h;
        if (cq < 12) {
          __hip_bfloat162 h;
          h.x = __float2bfloat16(prl);
          h.y = __float2bfloat16(prh);
          *(unsigned int*)&prod[s * KS + i * NC_A + c4] = *(unsigned int*)&h;
        } else {
          dsum += prl + prh;
        }
      }
      // dword 1: channels 4cq+2, 4cq+3
      {
        float pf_l = w00 * bf_lo(u00[i].y) + w01 * bf_lo(u01[i].y) +
                     w10 * bf_lo(u10[i].y) + w11 * bf_lo(u11[i].y);
        float pf_h = w00 * bf_hi(u00[i].y) + w01 * bf_hi(u01[i].y) +
                     w10 * bf_hi(u10[i].y) + w11 * bf_hi(u11[i].y);
        float lal = bf_lo(ul[i].z), lbl = bf_hi(ul[i].z);
        float lah = bf_lo(ul[i].w), lbh = bf_hi(ul[i].w);
        float lf_l = lal + lw * (lbl - lal);
        float lf_h = lah + lw * (lbh - lah);
        float prl = pf_l * lf_l, prh = pf_h * lf_h;
        if (cq < 12) {
          __hip_bfloat162 h;
          h.x = __float2bfloat16(prl);
          h.y = __float2bfloat16(prh);
          *(unsigned int*)&prod[s * KS + i * NC_A + c4 + 2] = *(unsigned int*)&h;
        } else {
          dsum += prl + prh;
        }
      }
    }
    // density reduce across channel-quads 12..15 (4-aligned lane groups)
    dsum += __shfl_xor(dsum, 1);
    dsum += __shfl_xor(dsum, 2);
    if (cq == 12 && n0 + s < n_total) {
      int pn = __float_as_int(cp[18]);
      out[pn] = dsum;
    }
  }
  __syncthreads();

  // Phase 2: app = prod(64x144) @ W^T via mfma 16x16x32 bf16, B from Wg
  const int srow = lane & 15, quad = lane >> 4;
  f32x4 acc0 = {0.f, 0.f, 0.f, 0.f}, acc1 = {0.f, 0.f, 0.f, 0.f};
  const short* prodS = (const short*)prod;
  const short* WgS   = (const short*)Wg;
  const int arow = (wave * 16 + srow) * KS;
  #pragma unroll
  for (int kt = 0; kt < 5; ++kt) {
    short8 a  = *(const short8*)&prodS[arow + kt * 32 + quad * 8];
    short8 b0 = *(const short8*)&WgS[(kt * 64 + lane) * 8];
    short8 b1 = *(const short8*)&WgS[((5 + kt) * 64 + lane) * 8];
    acc0 = __builtin_amdgcn_mfma_f32_16x16x32_bf16(a, b0, acc0, 0, 0, 0);
    acc1 = __builtin_amdgcn_mfma_f32_16x16x32_bf16(a, b1, acc1, 0, 0, 0);
  }
  // C/D layout: col(d) = lane&15, row(sample slot) = quad*4 + reg
  float* outApp = out + n_total;
  #pragma unroll
  for (int r = 0; r < 4; ++r) {
    int slot = wave * 16 + quad * 4 + r;
    if (n0 + slot < n_total) {
      int pn = __float_as_int(cw[slot * CWS + 18]);
      outApp[(size_t)pn * APP_DIM + srow] = acc0[r];
      if (srow < APP_DIM - 16)
        outApp[(size_t)pn * APP_DIM + 16 + srow] = acc1[r];
    }
  }
}

// ---------------------------------------------------------------------------
extern "C" void kernel_launch(void* const* d_in, const int* in_sizes, int n_in,
                              void* d_out, int out_size, void* d_ws, size_t ws_size,
                              hipStream_t stream) {
  const float* xyz   = (const float*)d_in[0];
  const float* plane = (const float*)d_in[1];
  const float* line  = (const float*)d_in[2];
  const float* W     = (const float*)d_in[3];
  float* out = (float*)d_out;
  const int N = in_sizes[0] / 3;

  char* ws = (char*)d_ws;
  __hip_bfloat16* Tp   = (__hip_bfloat16*)ws;                         // 34,560,000 B
  unsigned int*   TlP  = (unsigned int*)(ws + 34560000);              //    230,400 B
  __hip_bfloat16* Wg   = (__hip_bfloat16*)(ws + 34560000 + 230400);   //     10,240 B
  unsigned int*   hist = (unsigned int*)(ws + 34800640);              //    131,072 B
  float4*         xyzS = (float4*)(ws + 34931712);                    //  8,000,000 B

  prep<<<NPB2 + 16, 256, 0, stream>>>(plane, line, W, (unsigned int*)Tp, TlP, Wg);
  zero_hist<<<NBINS / 256, 256, 0, stream>>>(hist);
  bin_hist<<<(N + 255) / 256, 256, 0, stream>>>(xyz, hist, N);
  bin_scan<<<1, 256, 0, stream>>>(hist);
  bin_scatter<<<(N + 255) / 256, 256, 0, stream>>>(xyz, hist, xyzS, N);
  tensorf_main<<<(N + 63) / 64, 256, 0, stream>>>(
      xyzS, (const unsigned int*)Tp, TlP, Wg, out, N);
}

// Round 6
// 225.466 us; speedup vs baseline: 1.2434x; 1.2434x over previous
//
#include <hip/hip_runtime.h>
#include <hip/hip_bf16.h>

#define RES 300
#define NPLANE (RES * RES)   // 90000
#define NC_A 48
#define APP_DIM 27
#define KDIM 144             // 3 * NC_A
#define KS 168               // prod LDS row stride in shorts (336 B, 16B-aligned)

#define PT_TILES 1407        // ceil(90000 / 64) p-tiles per plane
#define NPB2 (3 * PT_TILES)  // 4221 plane-transpose blocks

// bf16 (packed in uint halves) -> f32
__device__ __forceinline__ float bf_lo(unsigned int u) { return __uint_as_float(u << 16); }
__device__ __forceinline__ float bf_hi(unsigned int u) { return __uint_as_float(u & 0xffff0000u); }

// ---------------------------------------------------------------------------
// Unified prep kernel (unchanged — passing since R1).
// ---------------------------------------------------------------------------
__global__ __launch_bounds__(256) void prep(
    const float* __restrict__ plane, const float* __restrict__ line,
    const float* __restrict__ W,
    unsigned int* __restrict__ TpUo, unsigned int* __restrict__ TlP,
    __hip_bfloat16* __restrict__ Wg) {
  __shared__ __align__(16) unsigned int lt[64 * 65];
  const int blk = blockIdx.x;
  const int tid = threadIdx.x;

  if (blk < NPB2) {
    const int i  = blk / PT_TILES;
    const int t0 = blk - i * PT_TILES;
    const int p0 = t0 * 64;

    const int cb   = (tid >> 4) * 4;
    const int poff = (tid & 15) * 4;
    const bool ok  = (p0 + poff) < NPLANE;

    const float* src = plane + (size_t)(i * 64 + cb) * NPLANE + p0 + poff;
    float4 v0, v1, v2, v3;
    v0 = v1 = v2 = v3 = make_float4(0.f, 0.f, 0.f, 0.f);
    if (ok) {
      v0 = *(const float4*)(src);
      v1 = *(const float4*)(src + NPLANE);
      v2 = *(const float4*)(src + 2 * NPLANE);
      v3 = *(const float4*)(src + 3 * NPLANE);
    }
    const int col = (tid >> 4) * 2;
    const float* f0 = &v0.x; const float* f1 = &v1.x;
    const float* f2 = &v2.x; const float* f3 = &v3.x;
    #pragma unroll
    for (int j = 0; j < 4; ++j) {
      __hip_bfloat162 ha, hb;
      ha.x = __float2bfloat16(f0[j]);
      ha.y = __float2bfloat16(f1[j]);
      hb.x = __float2bfloat16(f2[j]);
      hb.y = __float2bfloat16(f3[j]);
      uint2 u;
      u.x = *(unsigned int*)&ha;
      u.y = *(unsigned int*)&hb;
      *(uint2*)&lt[(poff + j) * 34 + col] = u;
    }
    __syncthreads();
    #pragma unroll
    for (int pass = 0; pass < 2; ++pass) {
      int p  = (tid >> 3) + pass * 32;
      int c4 = (tid & 7) * 4;
      if (p0 + p < NPLANE) {
        uint2 a = *(const uint2*)&lt[p * 34 + c4];
        uint2 b = *(const uint2*)&lt[p * 34 + c4 + 2];
        uint4 w; w.x = a.x; w.y = a.y; w.z = b.x; w.w = b.y;
        *(uint4*)&TpUo[((size_t)(i * NPLANE + p0 + p)) * 32 + c4] = w;
      }
    }
  } else if (blk < NPB2 + 15) {
    const int b  = blk - NPB2;
    const int i  = b / 5;
    const int y0 = (b % 5) * 64;
    const int yl = tid & 63;
    const int cq = tid >> 6;
    #pragma unroll
    for (int k = 0; k < 16; ++k) {
      int c = cq * 16 + k;
      int y = y0 + yl;
      float a = 0.f, bv = 0.f;
      if (y < RES) {
        const float* row = line + (i * 64 + c) * RES;
        a  = row[y];
        bv = row[min(y + 1, RES - 1)];
      }
      __hip_bfloat162 h;
      h.x = __float2bfloat16(a);
      h.y = __float2bfloat16(bv);
      lt[yl * 65 + c] = *(unsigned int*)&h;
    }
    __syncthreads();
    #pragma unroll
    for (int k = 0; k < 16; ++k) {
      int ylc = k * 4 + cq;
      int c   = tid & 63;
      int y   = y0 + ylc;
      if (y < RES) TlP[((size_t)i * RES + y) * 64 + c] = lt[ylc * 65 + c];
    }
  } else {
    for (int idx = tid; idx < 2 * 5 * 64 * 8; idx += 256) {
      int j    = idx & 7;
      int lane = (idx >> 3) & 63;
      int kt   = (idx >> 9) % 5;
      int tile = idx / (5 * 64 * 8);
      int n = tile * 16 + (lane & 15);
      int k = kt * 32 + (lane >> 4) * 8 + j;
      float v = (n < APP_DIM && k < KDIM) ? W[n * KDIM + k] : 0.f;
      Wg[idx] = __float2bfloat16(v);
    }
  }
}

// ---------------------------------------------------------------------------
// Main kernel: fused gather + blend + sigma + MFMA projection.
// Channel-OCTET scheme: lane&7 = channel octet (8 channels), lane>>3 =
// sample slot -> 8 samples per wave-iteration, only 2 phase-1 iterations.
// All gathers are uint4 (16B): 4 corner uint4 + 2 line uint4 per plane ->
// 36 VMEM/wave in phase 1 (was 60), each batch carrying 2x the data, so
// latency exposures per wave roughly halve. launch_bounds(256,4): VGPR cap
// 128 so an iteration's 72-dword load batch can live in registers.
// No sample sort (R5 proved locality is not the bound; sort chain cost
// outweighed its 10us main-kernel gain).
// LDS = 21504 (prod) + 4608 (cw) = 26112 B.
// ---------------------------------------------------------------------------
typedef __attribute__((ext_vector_type(8))) short short8;
typedef __attribute__((ext_vector_type(4))) float f32x4;

__global__ __launch_bounds__(256, 4) void tensorf_main(
    const float* __restrict__ xyz, const unsigned int* __restrict__ TpU,
    const unsigned int* __restrict__ TlP, const __hip_bfloat16* __restrict__ Wg,
    float* __restrict__ out, int n_total) {
  __shared__ __hip_bfloat16 prod[64 * KS];
  __shared__ float cw[64 * 18];

  const int tid  = threadIdx.x;
  const int lane = tid & 63;
  const int wave = tid >> 6;
  const int n0   = blockIdx.x * 64;

  // zero prod k-pad [144,168)
  for (int j = tid; j < 64 * 12; j += 256) {
    int s = j / 12, kk = (j % 12) * 2;
    *(unsigned int*)&prod[s * KS + KDIM + kk] = 0u;
  }

  // Phase 0: per-sample precompute (exact passing R0/R3 form).
  if (tid < 64) {
    int n = min(n0 + tid, n_total - 1);
    float crd[3] = {xyz[3 * n], xyz[3 * n + 1], xyz[3 * n + 2]};
    const int m0s[3] = {0, 0, 1}, m1s[3] = {1, 2, 2}, vms[3] = {2, 1, 0};
    float* c = &cw[tid * 18];
    #pragma unroll
    for (int i = 0; i < 3; ++i) {
      float ix = fminf(fmaxf((crd[m0s[i]] + 1.f) * 149.5f, 0.f), 299.f);
      float iy = fminf(fmaxf((crd[m1s[i]] + 1.f) * 149.5f, 0.f), 299.f);
      float ly = fminf(fmaxf((crd[vms[i]] + 1.f) * 149.5f, 0.f), 299.f);
      float x0f = fminf(floorf(ix), 298.f);
      float y0f = fminf(floorf(iy), 298.f);
      float l0f = fminf(floorf(ly), 298.f);
      float wx = ix - x0f, wy = iy - y0f, lwy = ly - l0f;
      int cell = i * NPLANE + (int)y0f * RES + (int)x0f;   // < 2^19
      int lidx = i * RES + (int)l0f;                       // < 2^10
      c[i * 6 + 0] = __int_as_float(cell | (lidx << 19));
      c[i * 6 + 1] = (1.f - wx) * (1.f - wy);
      c[i * 6 + 2] = wx * (1.f - wy);
      c[i * 6 + 3] = (1.f - wx) * wy;
      c[i * 6 + 4] = wx * wy;
      c[i * 6 + 5] = lwy;
    }
  }
  __syncthreads();

  // Phase 1: 2 iterations, 8 samples/wave-iter, 8 channels/lane, uint4 loads
  const int c8    = lane & 7;   // channel octet -> channels 8c8..8c8+7
  const int sslot = lane >> 3;  // sample slot within iteration group
  const int cu    = c8 * 4;     // uint offset of octet within TpU row

  #pragma unroll
  for (int it = 0; it < 2; ++it) {
    const int s = wave * 16 + it * 8 + sslot;
    const float* cp = &cw[s * 18];

    // batched load phase: 18 x uint4 VMEM (72 dwords) before any use
    unsigned int uc[3][4][4];   // [plane][corner][dword]
    unsigned int uln[3][8];     // [plane][channel-in-octet] line packs
    float wgt[3][5];
    #pragma unroll
    for (int i = 0; i < 3; ++i) {
      float2 q0 = *(const float2*)&cp[i * 6];       // pack, w00
      float2 q1 = *(const float2*)&cp[i * 6 + 2];   // w01, w10
      float2 q2 = *(const float2*)&cp[i * 6 + 4];   // w11, lwy
      int pk   = __float_as_int(q0.x);
      int cell = pk & 0x7FFFF;
      int lidx = pk >> 19;
      int bidx = cell * 32 + cu;                    // uint index into TpU
      *(uint4*)&uc[i][0][0] = *(const uint4*)&TpU[bidx];
      *(uint4*)&uc[i][1][0] = *(const uint4*)&TpU[bidx + 32];
      *(uint4*)&uc[i][2][0] = *(const uint4*)&TpU[bidx + RES * 32];
      *(uint4*)&uc[i][3][0] = *(const uint4*)&TpU[bidx + RES * 32 + 32];
      *(uint4*)&uln[i][0]   = *(const uint4*)&TlP[(lidx << 6) + c8 * 8];
      *(uint4*)&uln[i][4]   = *(const uint4*)&TlP[(lidx << 6) + c8 * 8 + 4];
      wgt[i][0] = q0.y; wgt[i][1] = q1.x; wgt[i][2] = q1.y;
      wgt[i][3] = q2.x; wgt[i][4] = q2.y;
    }

    // blend phase
    float dsum = 0.f;
    #pragma unroll
    for (int i = 0; i < 3; ++i) {
      float w00 = wgt[i][0], w01 = wgt[i][1], w10 = wgt[i][2];
      float w11 = wgt[i][3], lw = wgt[i][4];
      unsigned int res[4];
      #pragma unroll
      for (int d = 0; d < 4; ++d) {   // dword d: channels 8c8+2d, 8c8+2d+1
        float pf_l = w00 * bf_lo(uc[i][0][d]) + w01 * bf_lo(uc[i][1][d]) +
                     w10 * bf_lo(uc[i][2][d]) + w11 * bf_lo(uc[i][3][d]);
        float pf_h = w00 * bf_hi(uc[i][0][d]) + w01 * bf_hi(uc[i][1][d]) +
                     w10 * bf_hi(uc[i][2][d]) + w11 * bf_hi(uc[i][3][d]);
        unsigned int ua = uln[i][2 * d], ub = uln[i][2 * d + 1];
        float lal = bf_lo(ua), lbl = bf_hi(ua);
        float lah = bf_lo(ub), lbh = bf_hi(ub);
        float lf_l = lal + lw * (lbl - lal);
        float lf_h = lah + lw * (lbh - lah);
        float prl = pf_l * lf_l, prh = pf_h * lf_h;
        if (c8 < 6) {
          __hip_bfloat162 h;
          h.x = __float2bfloat16(prl);
          h.y = __float2bfloat16(prh);
          res[d] = *(unsigned int*)&h;
        } else {
          dsum += prl + prh;
        }
      }
      if (c8 < 6) {
        uint4 w4; w4.x = res[0]; w4.y = res[1]; w4.z = res[2]; w4.w = res[3];
        *(uint4*)&prod[s * KS + i * NC_A + c8 * 8] = w4;
      }
    }
    // density reduce: octets 6,7 (lanes differing in bit0 within each slot)
    dsum += __shfl_xor(dsum, 1);
    int n = n0 + s;
    if (c8 == 6 && n < n_total) out[n] = dsum;
  }
  __syncthreads();

  // Phase 2: app = prod(64x144) @ W^T via mfma 16x16x32 bf16, B from Wg
  const int srow = lane & 15, quad = lane >> 4;
  f32x4 acc0 = {0.f, 0.f, 0.f, 0.f}, acc1 = {0.f, 0.f, 0.f, 0.f};
  const short* prodS = (const short*)prod;
  const short* WgS   = (const short*)Wg;
  const int arow = (wave * 16 + srow) * KS;
  #pragma unroll
  for (int kt = 0; kt < 5; ++kt) {
    short8 a  = *(const short8*)&prodS[arow + kt * 32 + quad * 8];
    short8 b0 = *(const short8*)&WgS[(kt * 64 + lane) * 8];
    short8 b1 = *(const short8*)&WgS[((5 + kt) * 64 + lane) * 8];
    acc0 = __builtin_amdgcn_mfma_f32_16x16x32_bf16(a, b0, acc0, 0, 0, 0);
    acc1 = __builtin_amdgcn_mfma_f32_16x16x32_bf16(a, b1, acc1, 0, 0, 0);
  }
  // C/D layout: col(d) = lane&15, row(sample) = quad*4 + reg
  float* outApp = out + n_total;
  #pragma unroll
  for (int r = 0; r < 4; ++r) {
    int n = n0 + wave * 16 + quad * 4 + r;
    if (n < n_total) {
      outApp[(size_t)n * APP_DIM + srow] = acc0[r];
      if (srow < APP_DIM - 16)
        outApp[(size_t)n * APP_DIM + 16 + srow] = acc1[r];
    }
  }
}

// ---------------------------------------------------------------------------
extern "C" void kernel_launch(void* const* d_in, const int* in_sizes, int n_in,
                              void* d_out, int out_size, void* d_ws, size_t ws_size,
                              hipStream_t stream) {
  const float* xyz   = (const float*)d_in[0];
  const float* plane = (const float*)d_in[1];
  const float* line  = (const float*)d_in[2];
  const float* W     = (const float*)d_in[3];
  float* out = (float*)d_out;
  const int N = in_sizes[0] / 3;

  char* ws = (char*)d_ws;
  __hip_bfloat16* Tp  = (__hip_bfloat16*)ws;                        // 34,560,000 B
  unsigned int*   TlP = (unsigned int*)(ws + 34560000);             //    230,400 B
  __hip_bfloat16* Wg  = (__hip_bfloat16*)(ws + 34560000 + 230400);  //     10,240 B

  prep<<<NPB2 + 16, 256, 0, stream>>>(plane, line, W, (unsigned int*)Tp, TlP, Wg);
  tensorf_main<<<(N + 63) / 64, 256, 0, stream>>>(
      xyz, (const unsigned int*)Tp, TlP, Wg, out, N);
}